// Round 2
// baseline (6267.883 us; speedup 1.0000x reference)
//
#include <hip/hip_runtime.h>
#include <hip/hip_cooperative_groups.h>
#include <cstdint>
#include <cstddef>

// Problem constants (from reference: B=4, C=64, H=288, W=432, TEM=6)
#define NB 4
#define NC 64
#define HH 288
#define WW 432
#define PW 72                      // W / TEM
#define NV (HH*WW)                 // 124416 vertices
#define R_PER ((HH-1)*PW)          // 20664 row (vertical) edges per phase
#define C_PER (HH*(PW-1))          // 20448 col (horizontal) edges per phase
#define X_PER (HH*PW)              // 20736 cross edges per phase pair
#define PAIRW (R_PER + C_PER)      // 41112 weight-layout per-phase block
#define ROWS_TOT (6*R_PER)         // 123984
#define ROWCOL (6*PAIRW)           // 246672
#define NE (ROWCOL + 5*X_PER)      // 350352 edges
#define NEB ((NE + 255)/256)       // 1369 blocks per batch for edge kernels
#define NEP (NEB*256)              // 350464 padded edge space (64-aligned)
#define NWORDS_P (NEP/32)          // 10952 alive-bitmask words per batch (padded)
#define NTREE (NV-1)               // 124415
#define NROUNDS 18                 // round 0 fused in key0 + rounds 1..17
#define CHUNK 4096
#define NCHUNK ((NE + CHUNK - 1)/CHUNK)   // 86
#define BARMAX 2048                // max cooperative blocks / arrival slots

typedef unsigned long long ull;

// ---- edge id -> endpoints, per the INDEX layout (rows ++ cols ++ cross) ----
__device__ __forceinline__ void index_uv(int e, int& u, int& v) {
    if (e < ROWS_TOT) {
        int t = e / R_PER, l = e - t * R_PER;
        int h = l / PW, x = l - h * PW;
        u = h * WW + t * PW + x; v = u + WW;
    } else if (e < ROWCOL) {
        int q = e - ROWS_TOT;
        int t = q / C_PER, l = q - t * C_PER;
        int h = l / (PW-1), x = l - h * (PW-1);
        u = h * WW + t * PW + x; v = u + 1;
    } else {
        int q = e - ROWCOL;
        int t = q / X_PER, l = q - t * X_PER;
        int h = l / PW, x = l - h * PW;
        u = h * WW + t * PW + x; v = u + PW;
    }
}

// root under parent forest; handles unbroken 2-cycles (mutual min edge) by
// rooting the smaller id — exactly the reference's (gp==idx)&(idx<parent) rule.
__device__ __forceinline__ int rootOf(const int* __restrict__ par, int c) {
    while (true) {
        int p = par[c];
        if (p == c) return c;
        int pp = par[p];
        if (pp == c) return c < p ? c : p;
        c = p;
    }
}

// Hand-rolled grid barrier. cg::grid().sync() on this ROCm idles ~65 us per
// sync (s_sleep backoff spin) — measured round 1: 2610 us at 1.5% VALUBusy.
// Here: each block release-stores its epoch into its own arrival slot (no
// atomic contention); block 0's 256 threads acquire-poll all slots, then
// thread 0 release-stores the padded release flag; other blocks spin on it.
// HB chain: arrival(rel) -> block0 acquire -> __syncthreads -> flag(rel) ->
// spinner acquire, so all pre-barrier writes are visible device-wide.
__device__ __forceinline__ void grid_barrier(unsigned* arrive, unsigned* rel,
                                             unsigned ep, int nblk) {
    __syncthreads();
    if (blockIdx.x == 0) {
        for (int i = (int)threadIdx.x; i < nblk; i += 256) {
            if (i == 0) continue;
            while (__hip_atomic_load(&arrive[i], __ATOMIC_ACQUIRE,
                                     __HIP_MEMORY_SCOPE_AGENT) != ep) { }
        }
        __syncthreads();
        if (threadIdx.x == 0)
            __hip_atomic_store(rel, ep, __ATOMIC_RELEASE,
                               __HIP_MEMORY_SCOPE_AGENT);
    } else {
        if (threadIdx.x == 0) {
            __hip_atomic_store(&arrive[blockIdx.x], ep, __ATOMIC_RELEASE,
                               __HIP_MEMORY_SCOPE_AGENT);
            while (__hip_atomic_load(rel, __ATOMIC_ACQUIRE,
                                     __HIP_MEMORY_SCOPE_AGENT) != ep) {
                __builtin_amdgcn_s_sleep(1);
            }
        }
        __syncthreads();
    }
}

__global__ __launch_bounds__(256) void init_kernel(int* comp, int* parent,
                                                   ull* minkey, unsigned char* mask,
                                                   unsigned* aliveW,
                                                   int* found, int* done,
                                                   unsigned* bar) {
    int i = blockIdx.x * 256 + threadIdx.x;
    int b = blockIdx.y;
    if (i < NV) {
        comp[(size_t)b*NV + i] = i;
        parent[(size_t)b*NV + i] = i;
        minkey[(size_t)b*NV + i] = ~0ULL;
    }
    if (i < NE) mask[(size_t)b*NE + i] = 0;
    if (i < NWORDS_P) aliveW[(size_t)b*NWORDS_P + i] = 0xffffffffu;
    if (b == 0 && i < BARMAX + 128) bar[i] = 0;
    if (b == 0 && i < NB) { found[i] = 1; found[NB + i] = 0; done[i] = 0; }
}

// Stencil key kernel fused with Borůvka round 0 (~25 us, HBM-bound).
__global__ __launch_bounds__(256) void key0_kernel(const float* __restrict__ fm,
                                                   ull* __restrict__ keys,
                                                   ull* __restrict__ minkey) {
    int i = blockIdx.x * 256 + threadIdx.x;
    int b = blockIdx.y;
    if (i >= NV) return;
    int h = i / WW, x = i - h * WW;
    int t = x / PW, xr = x - t * PW;
    bool hv = (h < HH-1);
    bool hh = (xr < PW-1);
    bool hx = (x < WW-PW);
    int ov = hv ? WW : 0;          // invalid -> reload self, diff = 0
    int oh = hh ? 1  : 0;
    int ox = hx ? PW : 0;
    const float* base = fm + (size_t)b * NC * NV + i;
    float sv = 0.f, sh_ = 0.f, sx = 0.f;
    #pragma unroll 8
    for (int ch = 0; ch < NC; ++ch) {
        const float* p = base + (size_t)ch * NV;
        float f0 = p[0];
        float dv = f0 - p[ov];
        float dh = f0 - p[oh];
        float dx = f0 - p[ox];
        sv += dv * dv; sh_ += dh * dh; sx += dx * dx;
    }
    ull* mk = minkey + (size_t)b * NV;
    ull* ky = keys + (size_t)b * NE;
    if (hv) {
        int e = t * PAIRW + h * PW + xr;
        ull k = ((ull)__float_as_uint(sv) << 32) | (unsigned int)e;
        ky[e] = k;
        int u, v; index_uv(e, u, v);
        atomicMin(&mk[u], k); atomicMin(&mk[v], k);
    }
    if (hh) {
        int e = t * PAIRW + R_PER + h * (PW-1) + xr;
        ull k = ((ull)__float_as_uint(sh_) << 32) | (unsigned int)e;
        ky[e] = k;
        int u, v; index_uv(e, u, v);
        atomicMin(&mk[u], k); atomicMin(&mk[v], k);
    }
    if (hx) {
        int e = ROWCOL + t * X_PER + h * PW + xr;
        ull k = ((ull)__float_as_uint(sx) << 32) | (unsigned int)e;
        ky[e] = k;
        int u, v; index_uv(e, u, v);
        atomicMin(&mk[u], k); atomicMin(&mk[v], k);
    }
}

// Persistent cooperative kernel: round-0 select + rounds 1..17 (scan+select),
// custom grid barrier between phases, uniform early break on convergence.
// Batches run in PARALLEL: b = blockIdx.x & 3 (round 1 serialized them — 4x
// longer dependent-load chains). Grid-stride segments stay 64-aligned
// (per-batch thread base and stride are multiples of 64), so the wave-ballot
// alive-word rewrite logic is unchanged.
__global__ __launch_bounds__(256, 8) void rounds_kernel(
        const ull* __restrict__ keys,
        int* __restrict__ comp,
        int* __restrict__ parent,
        ull* __restrict__ minkey,
        unsigned char* __restrict__ mask,
        unsigned* __restrict__ aliveW,
        int* __restrict__ found,
        int* __restrict__ done,
        unsigned* __restrict__ bar)
{
    const int tid = threadIdx.x;
    const int nblk = gridDim.x;
    const int b = blockIdx.x & 3;                 // batch of this block
    const int tb = (blockIdx.x >> 2) * 256 + tid; // thread index within batch
    const int tstride = (nblk >> 2) * 256;        // threads per batch (mult of 64)
    const int lane = tid & 63;
    unsigned* arrive = bar;
    unsigned* rel = bar + BARMAX + 64;            // padded: no line sharing
    unsigned ep = 0;

    const size_t offV = (size_t)b * NV;
    unsigned* aw = aliveW + (size_t)b * NWORDS_P;
    const ull* ky = keys + (size_t)b * NE;
    int* cmp = comp + offV;
    int* par = parent + offV;
    ull* mk = minkey + offV;
    unsigned char* msk = mask + (size_t)b * NE;

    // Per component: read winning edge, mark mask, hook parent, reset minkey.
    auto select_phase = [&](const int* __restrict__ fCur, int* __restrict__ fNext) {
        if (blockIdx.x == 0 && tid < NB) {
            fNext[tid] = 0;
            if (__hip_atomic_load(&fCur[tid], __ATOMIC_RELAXED,
                                  __HIP_MEMORY_SCOPE_AGENT) == 0)
                done[tid] = 1;                    // monotone
        }
        int fc = __hip_atomic_load(&fCur[b], __ATOMIC_RELAXED,
                                   __HIP_MEMORY_SCOPE_AGENT);
        if (fc == 0) return;
        for (int c = tb; c < NV; c += tstride) {
            ull k = mk[c];
            int pr = c;
            if (k != ~0ULL) {
                mk[c] = ~0ULL;                    // reset only touched slots
                int e = (int)(k & 0xffffffffu);
                msk[e] = 1;                       // idempotent
                int u, v; index_uv(e, u, v);
                int cu = cmp[u], cv = cmp[v];
                pr = (cu == c) ? cv : cu;         // "other" component
            }
            if (par[c] != pr) par[c] = pr;
        }
    };

    // One Borůvka scan over this batch's edges; dead edges exit on bitmask
    // word read, deaths folded back via wave ballot (no atomics).
    auto scan_phase = [&](int* __restrict__ fCur) {
        if (__hip_atomic_load(&done[b], __ATOMIC_RELAXED,
                              __HIP_MEMORY_SCOPE_AGENT))
            return;                               // converged batch: skip
        for (int e = tb; e < NEP; e += tstride) {
            bool was = false, live = false;
            int cu = 0, cv = 0;
            ull k = 0;
            if (e < NE) was = (aw[e >> 5] >> (e & 31)) & 1;
            if (was) {
                int u, v; index_uv(e, u, v);
                int cu0 = cmp[u], cv0 = cmp[v];
                k = ky[e];                        // overlap load with chases
                cu = rootOf(par, cu0); if (cu0 != cu) cmp[u] = cu;  // benign race
                cv = rootOf(par, cv0); if (cv0 != cv) cmp[v] = cv;
                live = (cu != cv);
            }
            if (live) {
                if (k < mk[cu]) atomicMin(&mk[cu], k);  // pre-check filter
                if (k < mk[cv]) atomicMin(&mk[cv], k);
            }
            ull ball = __ballot(live ? 1 : 0);
            ull ballWas = __ballot(was ? 1 : 0);
            if (ball != ballWas) {                // deaths: rewrite 2 words
                int wbase = (e & ~63) >> 5;       // e 64-aligned per wave
                if (lane == 0)  aw[wbase]     = (unsigned)ball;
                if (lane == 32) aw[wbase + 1] = (unsigned)(ball >> 32);
            }
            if (ball && lane == __ffsll((long long)ball) - 1)
                fCur[b] = 1;                      // one store per wave
        }
    };

    // Round 0 select (found[0..NB) preset to 1 by init; comp = identity).
    select_phase(found, found + NB);
    grid_barrier(arrive, rel, ++ep, nblk);

    for (int r = 1; r < NROUNDS; ++r) {
        int* fCur  = found + (r & 1) * NB;
        int* fNext = found + ((r + 1) & 1) * NB;
        scan_phase(fCur);
        grid_barrier(arrive, rel, ++ep, nblk);
        select_phase(fCur, fNext);
        grid_barrier(arrive, rel, ++ep, nblk);
        // Uniform early exit: all blocks read identical post-barrier done
        // flags, so the break is grid-uniform (no divergent-barrier deadlock).
        int alldone =
            __hip_atomic_load(&done[0], __ATOMIC_RELAXED, __HIP_MEMORY_SCOPE_AGENT) &
            __hip_atomic_load(&done[1], __ATOMIC_RELAXED, __HIP_MEMORY_SCOPE_AGENT) &
            __hip_atomic_load(&done[2], __ATOMIC_RELAXED, __HIP_MEMORY_SCOPE_AGENT) &
            __hip_atomic_load(&done[3], __ATOMIC_RELAXED, __HIP_MEMORY_SCOPE_AGENT);
        if (alldone) break;
    }
}

__global__ __launch_bounds__(256) void count_kernel(const unsigned char* __restrict__ mask,
                                                    int* __restrict__ counts) {
    int b = blockIdx.y, ck = blockIdx.x, t = threadIdx.x;
    const unsigned char* m = mask + (size_t)b * NE;
    int base_e = ck * CHUNK + t * 16;
    int cnt = 0;
    #pragma unroll
    for (int i = 0; i < 16; ++i) {
        int e = base_e + i;
        if (e < NE && m[e]) cnt++;
    }
    __shared__ int sh[256];
    sh[t] = cnt;
    __syncthreads();
    for (int o = 128; o > 0; o >>= 1) {
        if (t < o) sh[t] += sh[t + o];
        __syncthreads();
    }
    if (t == 0) counts[b * NCHUNK + ck] = sh[0];
}

// Write with inline offset computation (reduce over counts[0..ck-1]).
__global__ __launch_bounds__(256) void write_kernel(const unsigned char* __restrict__ mask,
                                                    const int* __restrict__ counts,
                                                    int* __restrict__ out) {
    int b = blockIdx.y, ck = blockIdx.x, t = threadIdx.x;
    __shared__ int sh[256];
    __shared__ int shOff[128];
    shOff[t & 127] = 0;
    __syncthreads();
    if (t < NCHUNK && t < ck) shOff[t] = counts[b * NCHUNK + t];
    __syncthreads();
    for (int o = 64; o > 0; o >>= 1) {
        if (t < o) shOff[t] += shOff[t + o];
        __syncthreads();
    }
    int blockOff = shOff[0];

    const unsigned char* m = mask + (size_t)b * NE;
    int base_e = ck * CHUNK + t * 16;
    int cnt = 0;
    #pragma unroll
    for (int i = 0; i < 16; ++i) {
        int e = base_e + i;
        if (e < NE && m[e]) cnt++;
    }
    sh[t] = cnt;
    __syncthreads();
    for (int o = 1; o < 256; o <<= 1) {          // Hillis-Steele inclusive scan
        int v = 0;
        if (t >= o) v = sh[t - o];
        __syncthreads();
        sh[t] += v;
        __syncthreads();
    }
    int pos = blockOff + (sh[t] - cnt);
    for (int i = 0; i < 16; ++i) {
        int e = base_e + i;
        if (e < NE && m[e]) {
            if (pos < NTREE) out[(size_t)b * NTREE + pos] = e;
            pos++;
        }
    }
}

extern "C" void kernel_launch(void* const* d_in, const int* in_sizes, int n_in,
                              void* d_out, int out_size, void* d_ws, size_t ws_size,
                              hipStream_t stream) {
    const float* fm = (const float*)d_in[0];
    int* out = (int*)d_out;   // reference output dtype is int32

    char* ws = (char*)d_ws;
    size_t off = 0;
    auto alloc = [&](size_t bytes) -> void* {
        void* p = ws + off;
        off += (bytes + 255) & ~(size_t)255;
        return p;
    };
    ull* keys    = (ull*)alloc((size_t)NB * NE * 8);
    ull* minkey  = (ull*)alloc((size_t)NB * NV * 8);
    int* comp    = (int*)alloc((size_t)NB * NV * 4);
    int* parent  = (int*)alloc((size_t)NB * NV * 4);
    unsigned char* mask = (unsigned char*)alloc((size_t)NB * NE);
    unsigned* aliveW = (unsigned*)alloc((size_t)NB * NWORDS_P * 4);
    int* counts  = (int*)alloc((size_t)NB * NCHUNK * 4);
    int* found   = (int*)alloc(2 * NB * 4);
    int* done    = (int*)alloc(NB * 4);
    unsigned* bar = (unsigned*)alloc((BARMAX + 128) * 4);

    dim3 blk(256);
    dim3 gE(NEB, NB);
    dim3 gV((NV + 255) / 256, NB);

    init_kernel<<<gE, blk, 0, stream>>>(comp, parent, minkey, mask, aliveW,
                                        found, done, bar);
    key0_kernel<<<gV, blk, 0, stream>>>(fm, keys, minkey);

    // Persistent cooperative kernel for all Borůvka rounds. 16 VGPRs, so
    // 8 blocks/CU is attainable; occupancy query clamps defensively (host
    // query only — graph-capture safe; cached across calls).
    static int nblk = 0;
    if (nblk == 0) {
        int perCU = 0;
        if (hipOccupancyMaxActiveBlocksPerMultiprocessor(
                &perCU, reinterpret_cast<const void*>(rounds_kernel), 256, 0) != hipSuccess
            || perCU < 1)
            perCU = 4;
        long cap = (long)perCU * 256;            // 256 CUs
        if (cap > BARMAX) cap = BARMAX;
        nblk = (int)(cap & ~3L);                 // batch split needs %4 == 0
        if (nblk < 4) nblk = 4;
    }
    void* args[] = { (void*)&keys, (void*)&comp, (void*)&parent, (void*)&minkey,
                     (void*)&mask, (void*)&aliveW, (void*)&found, (void*)&done,
                     (void*)&bar };
    hipLaunchCooperativeKernel(reinterpret_cast<void*>(rounds_kernel),
                               dim3(nblk), dim3(256), args, 0, stream);

    count_kernel<<<dim3(NCHUNK, NB), blk, 0, stream>>>(mask, counts);
    write_kernel<<<dim3(NCHUNK, NB), blk, 0, stream>>>(mask, counts, out);
}

// Round 3
// 636.903 us; speedup vs baseline: 9.8412x; 9.8412x over previous
//
#include <hip/hip_runtime.h>
#include <cstdint>
#include <cstddef>

// Problem constants (from reference: B=4, C=64, H=288, W=432, TEM=6)
#define NB 4
#define NC 64
#define HH 288
#define WW 432
#define PW 72                      // W / TEM
#define NV (HH*WW)                 // 124416 vertices
#define R_PER ((HH-1)*PW)          // 20664 row (vertical) edges per phase
#define C_PER (HH*(PW-1))          // 20448 col (horizontal) edges per phase
#define X_PER (HH*PW)              // 20736 cross edges per phase pair
#define PAIRW (R_PER + C_PER)      // 41112 weight-layout per-phase block
#define ROWS_TOT (6*R_PER)         // 123984
#define ROWCOL (6*PAIRW)           // 246672
#define NE (ROWCOL + 5*X_PER)      // 350352 edges
#define NEB ((NE + 255)/256)       // 1369 blocks per batch for edge kernels
#define NTREE (NV-1)               // 124415
#define NROUNDS 18                 // round 0 fused in key0 + rounds 1..17
#define CHUNK 4096
#define NCHUNK ((NE + CHUNK - 1)/CHUNK)   // 86
#define CSTR 32                    // per-batch counter stride (ints) = 128B pad
#define SLB 128                    // scan_list blocks per batch

typedef unsigned long long ull;

// ---- edge id -> endpoints, per the INDEX layout (rows ++ cols ++ cross) ----
__device__ __forceinline__ void index_uv(int e, int& u, int& v) {
    if (e < ROWS_TOT) {
        int t = e / R_PER, l = e - t * R_PER;
        int h = l / PW, x = l - h * PW;
        u = h * WW + t * PW + x; v = u + WW;
    } else if (e < ROWCOL) {
        int q = e - ROWS_TOT;
        int t = q / C_PER, l = q - t * C_PER;
        int h = l / (PW-1), x = l - h * (PW-1);
        u = h * WW + t * PW + x; v = u + 1;
    } else {
        int q = e - ROWCOL;
        int t = q / X_PER, l = q - t * X_PER;
        int h = l / PW, x = l - h * PW;
        u = h * WW + t * PW + x; v = u + PW;
    }
}

// root under parent forest; handles unbroken 2-cycles (mutual min edge) by
// rooting the smaller id — exactly the reference's (gp==idx)&(idx<parent) rule.
__device__ __forceinline__ int rootOf(const int* __restrict__ par, int c) {
    while (true) {
        int p = par[c];
        if (p == c) return c;
        int pp = par[p];
        if (pp == c) return c < p ? c : p;
        c = p;
    }
}

__global__ __launch_bounds__(256) void init_kernel(int* comp, int* parent,
                                                   ull* minkey, unsigned char* mask,
                                                   int* cnt, int* found, int* done) {
    int i = blockIdx.x * 256 + threadIdx.x;
    int b = blockIdx.y;
    if (i < NV) {
        comp[(size_t)b*NV + i] = i;
        parent[(size_t)b*NV + i] = i;
        minkey[(size_t)b*NV + i] = ~0ULL;
    }
    if (i < NE) mask[(size_t)b*NE + i] = 0;
    if (b == 0 && i < 2*NB*CSTR) cnt[i] = 0;
    if (b == 0 && i < NB) { found[i] = 1; found[NB + i] = 0; done[i] = 0; }
}

// Stencil key kernel fused with Borůvka round 0 (~25 us, HBM-bound: 127 MB
// minimum input read — near roofline already).
__global__ __launch_bounds__(256) void key0_kernel(const float* __restrict__ fm,
                                                   ull* __restrict__ keys,
                                                   ull* __restrict__ minkey) {
    int i = blockIdx.x * 256 + threadIdx.x;
    int b = blockIdx.y;
    if (i >= NV) return;
    int h = i / WW, x = i - h * WW;
    int t = x / PW, xr = x - t * PW;
    bool hv = (h < HH-1);
    bool hh = (xr < PW-1);
    bool hx = (x < WW-PW);
    int ov = hv ? WW : 0;          // invalid -> reload self, diff = 0
    int oh = hh ? 1  : 0;
    int ox = hx ? PW : 0;
    const float* base = fm + (size_t)b * NC * NV + i;
    float sv = 0.f, sh_ = 0.f, sx = 0.f;
    #pragma unroll 8
    for (int ch = 0; ch < NC; ++ch) {
        const float* p = base + (size_t)ch * NV;
        float f0 = p[0];
        float dv = f0 - p[ov];
        float dh = f0 - p[oh];
        float dx = f0 - p[ox];
        sv += dv * dv; sh_ += dh * dh; sx += dx * dx;
    }
    ull* mk = minkey + (size_t)b * NV;
    ull* ky = keys + (size_t)b * NE;
    if (hv) {
        int e = t * PAIRW + h * PW + xr;
        ull k = ((ull)__float_as_uint(sv) << 32) | (unsigned int)e;
        ky[e] = k;
        int u, v; index_uv(e, u, v);
        atomicMin(&mk[u], k); atomicMin(&mk[v], k);
    }
    if (hh) {
        int e = t * PAIRW + R_PER + h * (PW-1) + xr;
        ull k = ((ull)__float_as_uint(sh_) << 32) | (unsigned int)e;
        ky[e] = k;
        int u, v; index_uv(e, u, v);
        atomicMin(&mk[u], k); atomicMin(&mk[v], k);
    }
    if (hx) {
        int e = ROWCOL + t * X_PER + h * PW + xr;
        ull k = ((ull)__float_as_uint(sx) << 32) | (unsigned int)e;
        ky[e] = k;
        int u, v; index_uv(e, u, v);
        atomicMin(&mk[u], k); atomicMin(&mk[v], k);
    }
}

// Round-1 scan: full sweep over all edges (everything alive after round 0's
// singleton hooks), PLUS compaction: surviving (cross-component) edge ids are
// emitted into list0/cnt[0] via block-aggregated atomics (1 global atomicAdd
// per 256-thread block; per-batch counters padded 128B apart). No early
// return — all threads participate in the emission __syncthreads.
__global__ __launch_bounds__(256) void scan_full_kernel(const ull* __restrict__ keys,
                                                        int* __restrict__ comp,
                                                        const int* __restrict__ parent,
                                                        ull* __restrict__ minkey,
                                                        int* __restrict__ list0,
                                                        int* __restrict__ cnt,
                                                        int* __restrict__ fCur) {
    const int tid = threadIdx.x;
    const int b = blockIdx.y;
    const int e = blockIdx.x * 256 + tid;
    const bool valid = e < NE;
    const size_t offV = (size_t)b * NV;
    const int* par = parent + offV;
    int* cmp = comp + offV;
    ull* mk = minkey + offV;
    const ull* ky = keys + (size_t)b * NE;

    bool live = false;
    if (valid) {
        int u, v; index_uv(e, u, v);
        int cu0 = cmp[u], cv0 = cmp[v];
        ull k = ky[e];                        // overlap load with chases
        int cu = rootOf(par, cu0); if (cu0 != cu) cmp[u] = cu;  // benign race
        int cv = rootOf(par, cv0); if (cv0 != cv) cmp[v] = cv;
        live = (cu != cv);
        if (live) {
            if (k < mk[cu]) atomicMin(&mk[cu], k);  // pre-check filter
            if (k < mk[cv]) atomicMin(&mk[cv], k);
        }
    }
    // block-aggregated emission
    __shared__ int s_wb[4];
    __shared__ int s_bcnt;
    __shared__ int s_gb;
    ull ball = __ballot(live ? 1 : 0);
    if (tid == 0) s_bcnt = 0;
    __syncthreads();
    if ((tid & 63) == 0) s_wb[tid >> 6] = ball ? atomicAdd(&s_bcnt, __popcll(ball)) : 0;
    __syncthreads();
    if (tid == 0 && s_bcnt) {
        s_gb = atomicAdd(&cnt[b * CSTR], s_bcnt);
        fCur[b] = 1;
    }
    __syncthreads();
    if (live) {
        int lane = tid & 63;
        int pos = s_gb + s_wb[tid >> 6] + __popcll(ball & ((1ull << lane) - 1));
        list0[(size_t)b * NE + pos] = e;
    }
}

// Rounds 2..17: scan over the compacted live-edge list (double-buffered).
// Reads list[rpar]/cnt[rpar], emits survivors into list[rpar^1]/cnt[rpar^1]
// (zeroed by the previous select). Fixed small grid, uniform grid-stride loop
// (nIter identical across the block so the emission __syncthreads are safe).
__global__ __launch_bounds__(256) void scan_list_kernel(const ull* __restrict__ keys,
                                                        int* __restrict__ comp,
                                                        const int* __restrict__ parent,
                                                        ull* __restrict__ minkey,
                                                        int* __restrict__ list0,
                                                        int* __restrict__ list1,
                                                        int* __restrict__ cnt,
                                                        int rpar,
                                                        int* __restrict__ fCur,
                                                        const int* __restrict__ done) {
    const int b = blockIdx.y;
    if (done[b]) return;                      // block-uniform: safe pre-sync exit
    const int tid = threadIdx.x;
    const int n = cnt[rpar * NB * CSTR + b * CSTR];
    int* cw = &cnt[(rpar ^ 1) * NB * CSTR + b * CSTR];
    const int* lr = (rpar ? list1 : list0) + (size_t)b * NE;
    int* lw = (rpar ? list0 : list1) + (size_t)b * NE;
    const size_t offV = (size_t)b * NV;
    const int* par = parent + offV;
    int* cmp = comp + offV;
    ull* mk = minkey + offV;
    const ull* ky = keys + (size_t)b * NE;

    const int stride = SLB * 256;
    const int nIter = (n + stride - 1) / stride;   // uniform across block
    __shared__ int s_wb[4];
    __shared__ int s_bcnt;
    __shared__ int s_gb;

    for (int it = 0; it < nIter; ++it) {
        int i = it * stride + blockIdx.x * 256 + tid;
        bool valid = i < n;
        bool live = false;
        int e = 0;
        if (valid) {
            e = lr[i];
            int u, v; index_uv(e, u, v);
            int cu0 = cmp[u], cv0 = cmp[v];
            ull k = ky[e];
            int cu = rootOf(par, cu0); if (cu0 != cu) cmp[u] = cu;  // benign race
            int cv = rootOf(par, cv0); if (cv0 != cv) cmp[v] = cv;
            live = (cu != cv);
            if (live) {
                if (k < mk[cu]) atomicMin(&mk[cu], k);
                if (k < mk[cv]) atomicMin(&mk[cv], k);
            }
        }
        ull ball = __ballot(live ? 1 : 0);
        if (tid == 0) s_bcnt = 0;
        __syncthreads();
        if ((tid & 63) == 0) s_wb[tid >> 6] = ball ? atomicAdd(&s_bcnt, __popcll(ball)) : 0;
        __syncthreads();
        if (tid == 0 && s_bcnt) {
            s_gb = atomicAdd(cw, s_bcnt);
            fCur[b] = 1;
        }
        __syncthreads();
        if (live) {
            int lane = tid & 63;
            int pos = s_gb + s_wb[tid >> 6] + __popcll(ball & ((1ull << lane) - 1));
            lw[pos] = e;
        }
    }
}

// Per component: read winning edge, mark mask, hook parent, reset minkey.
// The full-NV parent sweep (pr=c default) is load-bearing: it flattens stale
// hooks from previous rounds so rootOf only ever chases this round's forest.
// Also zeroes cnt[zpar] (the list buffer the just-finished scan consumed,
// which the NEXT scan will emit into).
__global__ __launch_bounds__(256) void select_kernel(const int* __restrict__ comp,
                                                     int* __restrict__ parent,
                                                     ull* __restrict__ minkey,
                                                     unsigned char* __restrict__ mask,
                                                     const int* __restrict__ foundCur,
                                                     int* __restrict__ foundNext,
                                                     int* __restrict__ done,
                                                     int* __restrict__ cnt,
                                                     int zpar) {
    int c = blockIdx.x * 256 + threadIdx.x;
    int b = blockIdx.y;
    int fc = foundCur[b];
    if (c == 0) {
        foundNext[b] = 0;
        cnt[zpar * NB * CSTR + b * CSTR] = 0;
        if (fc == 0) done[b] = 1;                // monotone; visible to later scans
    }
    if (fc == 0) return;
    if (c >= NV) return;
    size_t off = (size_t)b * NV;
    ull k = minkey[off + c];
    int par = c;
    if (k != ~0ULL) {
        minkey[off + c] = ~0ULL;                 // reset only touched slots
        int e = (int)(k & 0xffffffffu);
        mask[(size_t)b * NE + e] = 1;            // idempotent
        int u, v; index_uv(e, u, v);
        int cu = comp[off + u], cv = comp[off + v];
        par = (cu == c) ? cv : cu;               // "other" component
    }
    if (parent[off + c] != par) parent[off + c] = par;
}

__global__ __launch_bounds__(256) void count_kernel(const unsigned char* __restrict__ mask,
                                                    int* __restrict__ counts) {
    int b = blockIdx.y, ck = blockIdx.x, t = threadIdx.x;
    const unsigned char* m = mask + (size_t)b * NE;
    int base_e = ck * CHUNK + t * 16;
    int cnt = 0;
    #pragma unroll
    for (int i = 0; i < 16; ++i) {
        int e = base_e + i;
        if (e < NE && m[e]) cnt++;
    }
    __shared__ int sh[256];
    sh[t] = cnt;
    __syncthreads();
    for (int o = 128; o > 0; o >>= 1) {
        if (t < o) sh[t] += sh[t + o];
        __syncthreads();
    }
    if (t == 0) counts[b * NCHUNK + ck] = sh[0];
}

// Write with inline offset computation (reduce over counts[0..ck-1]).
__global__ __launch_bounds__(256) void write_kernel(const unsigned char* __restrict__ mask,
                                                    const int* __restrict__ counts,
                                                    int* __restrict__ out) {
    int b = blockIdx.y, ck = blockIdx.x, t = threadIdx.x;
    __shared__ int sh[256];
    __shared__ int shOff[128];
    shOff[t & 127] = 0;
    __syncthreads();
    if (t < NCHUNK && t < ck) shOff[t] = counts[b * NCHUNK + t];
    __syncthreads();
    for (int o = 64; o > 0; o >>= 1) {
        if (t < o) shOff[t] += shOff[t + o];
        __syncthreads();
    }
    int blockOff = shOff[0];

    const unsigned char* m = mask + (size_t)b * NE;
    int base_e = ck * CHUNK + t * 16;
    int cnt = 0;
    #pragma unroll
    for (int i = 0; i < 16; ++i) {
        int e = base_e + i;
        if (e < NE && m[e]) cnt++;
    }
    sh[t] = cnt;
    __syncthreads();
    for (int o = 1; o < 256; o <<= 1) {          // Hillis-Steele inclusive scan
        int v = 0;
        if (t >= o) v = sh[t - o];
        __syncthreads();
        sh[t] += v;
        __syncthreads();
    }
    int pos = blockOff + (sh[t] - cnt);
    for (int i = 0; i < 16; ++i) {
        int e = base_e + i;
        if (e < NE && m[e]) {
            if (pos < NTREE) out[(size_t)b * NTREE + pos] = e;
            pos++;
        }
    }
}

extern "C" void kernel_launch(void* const* d_in, const int* in_sizes, int n_in,
                              void* d_out, int out_size, void* d_ws, size_t ws_size,
                              hipStream_t stream) {
    const float* fm = (const float*)d_in[0];
    int* out = (int*)d_out;   // reference output dtype is int32

    char* ws = (char*)d_ws;
    size_t off = 0;
    auto alloc = [&](size_t bytes) -> void* {
        void* p = ws + off;
        off += (bytes + 255) & ~(size_t)255;
        return p;
    };
    ull* keys    = (ull*)alloc((size_t)NB * NE * 8);
    ull* minkey  = (ull*)alloc((size_t)NB * NV * 8);
    int* comp    = (int*)alloc((size_t)NB * NV * 4);
    int* parent  = (int*)alloc((size_t)NB * NV * 4);
    unsigned char* mask = (unsigned char*)alloc((size_t)NB * NE);
    int* list0   = (int*)alloc((size_t)NB * NE * 4);
    int* list1   = (int*)alloc((size_t)NB * NE * 4);
    int* cnt     = (int*)alloc(2 * NB * CSTR * 4);
    int* counts  = (int*)alloc((size_t)NB * NCHUNK * 4);
    int* found   = (int*)alloc(2 * NB * 4);
    int* done    = (int*)alloc(NB * 4);

    dim3 blk(256);
    dim3 gE(NEB, NB);
    dim3 gV((NV + 255) / 256, NB);
    dim3 gL(SLB, NB);

    init_kernel<<<gE, blk, 0, stream>>>(comp, parent, minkey, mask, cnt, found, done);
    key0_kernel<<<gV, blk, 0, stream>>>(fm, keys, minkey);

    // Round 0 select (found[0..NB) preset to 1 by init; comp = identity).
    select_kernel<<<gV, blk, 0, stream>>>(comp, parent, minkey, mask,
                                          found, found + NB, done, cnt, 0);
    // Round 1: full edge sweep + live-edge compaction into list0/cnt[0].
    scan_full_kernel<<<gE, blk, 0, stream>>>(keys, comp, parent, minkey,
                                             list0, cnt, found + NB);
    select_kernel<<<gV, blk, 0, stream>>>(comp, parent, minkey, mask,
                                          found + NB, found, done, cnt, 1);
    // Rounds 2..17: list-based scans. scan(r) reads list[r&1], emits
    // list[(r+1)&1]; select(r) zeroes cnt[r&1] for scan(r+1)'s emission.
    for (int r = 2; r < NROUNDS; ++r) {
        int* fCur  = found + (r & 1) * NB;
        int* fNext = found + ((r + 1) & 1) * NB;
        scan_list_kernel<<<gL, blk, 0, stream>>>(keys, comp, parent, minkey,
                                                 list0, list1, cnt, r & 1,
                                                 fCur, done);
        select_kernel<<<gV, blk, 0, stream>>>(comp, parent, minkey, mask,
                                              fCur, fNext, done, cnt, r & 1);
    }

    count_kernel<<<dim3(NCHUNK, NB), blk, 0, stream>>>(mask, counts);
    write_kernel<<<dim3(NCHUNK, NB), blk, 0, stream>>>(mask, counts, out);
}

// Round 4
// 583.167 us; speedup vs baseline: 10.7480x; 1.0921x over previous
//
#include <hip/hip_runtime.h>
#include <cstdint>
#include <cstddef>

// Problem constants (from reference: B=4, C=64, H=288, W=432, TEM=6)
#define NB 4
#define NC 64
#define HH 288
#define WW 432
#define PW 72                      // W / TEM
#define NV (HH*WW)                 // 124416 vertices
#define R_PER ((HH-1)*PW)          // 20664 row (vertical) edges per phase
#define C_PER (HH*(PW-1))          // 20448 col (horizontal) edges per phase
#define X_PER (HH*PW)              // 20736 cross edges per phase pair
#define PAIRW (R_PER + C_PER)      // 41112 weight-layout per-phase block
#define ROWS_TOT (6*R_PER)         // 123984
#define ROWCOL (6*PAIRW)           // 246672
#define NE (ROWCOL + 5*X_PER)      // 350352 edges
#define NEB ((NE + 255)/256)       // 1369 blocks per batch (init grid)
#define EPT 4                      // edges per thread (ILP: 4 indep chains)
#define NEB4 ((NE + 1023)/1024)    // 343 blocks per batch (scan_full)
#define NTREE (NV-1)               // 124415
#define NROUNDS 18                 // round 0 fused in key0 + rounds 1..17
#define CHUNK 4096
#define NCHUNK ((NE + CHUNK - 1)/CHUNK)   // 86
#define CSTR 32                    // per-batch counter stride (ints) = 128B pad
#define SLB 128                    // scan_list blocks per batch

typedef unsigned long long ull;

// ---- edge id -> endpoints, per the INDEX layout (rows ++ cols ++ cross) ----
__device__ __forceinline__ void index_uv(int e, int& u, int& v) {
    if (e < ROWS_TOT) {
        int t = e / R_PER, l = e - t * R_PER;
        int h = l / PW, x = l - h * PW;
        u = h * WW + t * PW + x; v = u + WW;
    } else if (e < ROWCOL) {
        int q = e - ROWS_TOT;
        int t = q / C_PER, l = q - t * C_PER;
        int h = l / (PW-1), x = l - h * (PW-1);
        u = h * WW + t * PW + x; v = u + 1;
    } else {
        int q = e - ROWCOL;
        int t = q / X_PER, l = q - t * X_PER;
        int h = l / PW, x = l - h * PW;
        u = h * WW + t * PW + x; v = u + PW;
    }
}

// root under parent forest; handles unbroken 2-cycles (mutual min edge) by
// rooting the smaller id — exactly the reference's (gp==idx)&(idx<parent) rule.
// rootOf2 takes the preloaded first hop p = par[c] so the common depth-1 case
// (p == c) completes with no additional dependent load.
__device__ __forceinline__ int rootOf2(const int* __restrict__ par, int c, int p) {
    while (true) {
        if (p == c) return c;
        int pp = par[p];
        if (pp == c) return c < p ? c : p;
        c = p; p = pp;
    }
}

__global__ __launch_bounds__(256) void init_kernel(int* comp, int* parent,
                                                   ull* minkey, unsigned char* mask,
                                                   int* cnt, int* found, int* done) {
    int i = blockIdx.x * 256 + threadIdx.x;
    int b = blockIdx.y;
    if (i < NV) {
        comp[(size_t)b*NV + i] = i;
        parent[(size_t)b*NV + i] = i;
        minkey[(size_t)b*NV + i] = ~0ULL;
    }
    if (i < NE) mask[(size_t)b*NE + i] = 0;
    if (b == 0 && i < 2*NB*CSTR) cnt[i] = 0;
    if (b == 0 && i < NB) { found[i] = 1; found[NB + i] = 0; done[i] = 0; }
}

// Stencil key kernel fused with Borůvka round 0 (~25 us, HBM-bound: 127 MB
// minimum input read — near roofline already).
__global__ __launch_bounds__(256) void key0_kernel(const float* __restrict__ fm,
                                                   ull* __restrict__ keys,
                                                   ull* __restrict__ minkey) {
    int i = blockIdx.x * 256 + threadIdx.x;
    int b = blockIdx.y;
    if (i >= NV) return;
    int h = i / WW, x = i - h * WW;
    int t = x / PW, xr = x - t * PW;
    bool hv = (h < HH-1);
    bool hh = (xr < PW-1);
    bool hx = (x < WW-PW);
    int ov = hv ? WW : 0;          // invalid -> reload self, diff = 0
    int oh = hh ? 1  : 0;
    int ox = hx ? PW : 0;
    const float* base = fm + (size_t)b * NC * NV + i;
    float sv = 0.f, sh_ = 0.f, sx = 0.f;
    #pragma unroll 8
    for (int ch = 0; ch < NC; ++ch) {
        const float* p = base + (size_t)ch * NV;
        float f0 = p[0];
        float dv = f0 - p[ov];
        float dh = f0 - p[oh];
        float dx = f0 - p[ox];
        sv += dv * dv; sh_ += dh * dh; sx += dx * dx;
    }
    ull* mk = minkey + (size_t)b * NV;
    ull* ky = keys + (size_t)b * NE;
    if (hv) {
        int e = t * PAIRW + h * PW + xr;
        ull k = ((ull)__float_as_uint(sv) << 32) | (unsigned int)e;
        ky[e] = k;
        int u, v; index_uv(e, u, v);
        atomicMin(&mk[u], k); atomicMin(&mk[v], k);
    }
    if (hh) {
        int e = t * PAIRW + R_PER + h * (PW-1) + xr;
        ull k = ((ull)__float_as_uint(sh_) << 32) | (unsigned int)e;
        ky[e] = k;
        int u, v; index_uv(e, u, v);
        atomicMin(&mk[u], k); atomicMin(&mk[v], k);
    }
    if (hx) {
        int e = ROWCOL + t * X_PER + h * PW + xr;
        ull k = ((ull)__float_as_uint(sx) << 32) | (unsigned int)e;
        ky[e] = k;
        int u, v; index_uv(e, u, v);
        atomicMin(&mk[u], k); atomicMin(&mk[v], k);
    }
}

// Round-1 scan: full sweep over all edges, 4 edges/thread with software
// pipelining — all independent loads (comp[u], comp[v], key, first parent
// hop of both endpoints) issue before any chase consumes them (round-3 PMC:
// VALUBusy 6%, HBM 12%, occ 69% => latency-bound single chains). Survivors
// compacted into list0/cnt[0] via per-wave 4-ballot prefix + 1 LDS atomic
// per wave + 1 global atomic per block.
__global__ __launch_bounds__(256) void scan_full_kernel(const ull* __restrict__ keys,
                                                        int* __restrict__ comp,
                                                        const int* __restrict__ parent,
                                                        ull* __restrict__ minkey,
                                                        int* __restrict__ list0,
                                                        int* __restrict__ cnt,
                                                        int* __restrict__ fCur) {
    const int tid = threadIdx.x;
    const int b = blockIdx.y;
    const int ebase = blockIdx.x * (256 * EPT) + tid;
    const size_t offV = (size_t)b * NV;
    const int* par = parent + offV;
    int* cmp = comp + offV;
    ull* mk = minkey + offV;
    const ull* ky = keys + (size_t)b * NE;

    int e[EPT], uu[EPT], vv[EPT], cu0[EPT], cv0[EPT], pu0[EPT], pv0[EPT];
    ull k[EPT];
    bool valid[EPT], live[EPT];
    #pragma unroll
    for (int j = 0; j < EPT; ++j) {
        e[j] = ebase + j * 256;
        valid[j] = e[j] < NE;
        int u = 0, v = 0;
        if (valid[j]) index_uv(e[j], u, v);
        uu[j] = u; vv[j] = v;
    }
    #pragma unroll
    for (int j = 0; j < EPT; ++j) {       // independent loads: comp + key
        cu0[j] = valid[j] ? cmp[uu[j]] : 0;
        cv0[j] = valid[j] ? cmp[vv[j]] : 0;
        k[j]   = valid[j] ? ky[e[j]] : 0;
    }
    #pragma unroll
    for (int j = 0; j < EPT; ++j) {       // independent loads: first par hop
        pu0[j] = valid[j] ? par[cu0[j]] : 0;
        pv0[j] = valid[j] ? par[cv0[j]] : 0;
    }
    #pragma unroll
    for (int j = 0; j < EPT; ++j) {
        live[j] = false;
        if (valid[j]) {
            int cu = rootOf2(par, cu0[j], pu0[j]);
            int cv = rootOf2(par, cv0[j], pv0[j]);
            if (cu0[j] != cu) cmp[uu[j]] = cu;   // benign race (fresh-root cache)
            if (cv0[j] != cv) cmp[vv[j]] = cv;
            live[j] = (cu != cv);
            if (live[j]) {
                if (k[j] < mk[cu]) atomicMin(&mk[cu], k[j]);  // pre-check filter
                if (k[j] < mk[cv]) atomicMin(&mk[cv], k[j]);
            }
        }
    }
    // block-aggregated emission (4 ballots, uniform control flow)
    __shared__ int s_w[4];
    __shared__ int s_bcnt;
    __shared__ int s_gb;
    const int lane = tid & 63;
    const int wid = tid >> 6;
    ull wl[EPT]; int wcnt = 0;
    #pragma unroll
    for (int j = 0; j < EPT; ++j) { wl[j] = __ballot(live[j] ? 1 : 0); wcnt += __popcll(wl[j]); }
    if (tid == 0) s_bcnt = 0;
    __syncthreads();
    if (lane == 0) s_w[wid] = wcnt ? atomicAdd(&s_bcnt, wcnt) : 0;
    __syncthreads();
    if (tid == 0 && s_bcnt) {
        s_gb = atomicAdd(&cnt[b * CSTR], s_bcnt);
        fCur[b] = 1;
    }
    __syncthreads();
    int pre = 0;
    #pragma unroll
    for (int j = 0; j < EPT; ++j) {
        if (live[j]) {
            int pos = s_gb + s_w[wid] + pre + __popcll(wl[j] & ((1ull << lane) - 1));
            list0[(size_t)b * NE + pos] = e[j];
        }
        pre += __popcll(wl[j]);
    }
}

// Rounds 2..17: scan over the compacted live-edge list (double-buffered),
// same 4-edges/thread pipelined structure. Reads list[rpar]/cnt[rpar], emits
// survivors into list[rpar^1]/cnt[rpar^1] (zeroed by the previous select).
// Fixed small grid, uniform grid-stride loop (nIter identical across block).
__global__ __launch_bounds__(256) void scan_list_kernel(const ull* __restrict__ keys,
                                                        int* __restrict__ comp,
                                                        const int* __restrict__ parent,
                                                        ull* __restrict__ minkey,
                                                        int* __restrict__ list0,
                                                        int* __restrict__ list1,
                                                        int* __restrict__ cnt,
                                                        int rpar,
                                                        int* __restrict__ fCur,
                                                        const int* __restrict__ done) {
    const int b = blockIdx.y;
    if (done[b]) return;                      // block-uniform: safe pre-sync exit
    const int tid = threadIdx.x;
    const int n = cnt[rpar * NB * CSTR + b * CSTR];
    int* cw = &cnt[(rpar ^ 1) * NB * CSTR + b * CSTR];
    const int* lr = (rpar ? list1 : list0) + (size_t)b * NE;
    int* lw = (rpar ? list0 : list1) + (size_t)b * NE;
    const size_t offV = (size_t)b * NV;
    const int* par = parent + offV;
    int* cmp = comp + offV;
    ull* mk = minkey + offV;
    const ull* ky = keys + (size_t)b * NE;

    const int stride = SLB * 256 * EPT;
    const int nIter = (n + stride - 1) / stride;   // uniform across block
    const int lane = tid & 63;
    const int wid = tid >> 6;
    __shared__ int s_w[4];
    __shared__ int s_bcnt;
    __shared__ int s_gb;

    for (int it = 0; it < nIter; ++it) {
        const int ibase = it * stride + blockIdx.x * (256 * EPT) + tid;
        int e[EPT], uu[EPT], vv[EPT], cu0[EPT], cv0[EPT], pu0[EPT], pv0[EPT];
        ull k[EPT];
        bool valid[EPT], live[EPT];
        #pragma unroll
        for (int j = 0; j < EPT; ++j) {
            int i = ibase + j * 256;
            valid[j] = i < n;
            e[j] = valid[j] ? lr[i] : 0;
        }
        #pragma unroll
        for (int j = 0; j < EPT; ++j) {
            int u = 0, v = 0;
            if (valid[j]) index_uv(e[j], u, v);
            uu[j] = u; vv[j] = v;
        }
        #pragma unroll
        for (int j = 0; j < EPT; ++j) {
            cu0[j] = valid[j] ? cmp[uu[j]] : 0;
            cv0[j] = valid[j] ? cmp[vv[j]] : 0;
            k[j]   = valid[j] ? ky[e[j]] : 0;
        }
        #pragma unroll
        for (int j = 0; j < EPT; ++j) {
            pu0[j] = valid[j] ? par[cu0[j]] : 0;
            pv0[j] = valid[j] ? par[cv0[j]] : 0;
        }
        #pragma unroll
        for (int j = 0; j < EPT; ++j) {
            live[j] = false;
            if (valid[j]) {
                int cu = rootOf2(par, cu0[j], pu0[j]);
                int cv = rootOf2(par, cv0[j], pv0[j]);
                if (cu0[j] != cu) cmp[uu[j]] = cu;   // benign race
                if (cv0[j] != cv) cmp[vv[j]] = cv;
                live[j] = (cu != cv);
                if (live[j]) {
                    if (k[j] < mk[cu]) atomicMin(&mk[cu], k[j]);
                    if (k[j] < mk[cv]) atomicMin(&mk[cv], k[j]);
                }
            }
        }
        ull wl[EPT]; int wcnt = 0;
        #pragma unroll
        for (int j = 0; j < EPT; ++j) { wl[j] = __ballot(live[j] ? 1 : 0); wcnt += __popcll(wl[j]); }
        if (tid == 0) s_bcnt = 0;
        __syncthreads();
        if (lane == 0) s_w[wid] = wcnt ? atomicAdd(&s_bcnt, wcnt) : 0;
        __syncthreads();
        if (tid == 0 && s_bcnt) {
            s_gb = atomicAdd(cw, s_bcnt);
            fCur[b] = 1;
        }
        __syncthreads();
        int pre = 0;
        #pragma unroll
        for (int j = 0; j < EPT; ++j) {
            if (live[j]) {
                int pos = s_gb + s_w[wid] + pre + __popcll(wl[j] & ((1ull << lane) - 1));
                lw[pos] = e[j];
            }
            pre += __popcll(wl[j]);
        }
    }
}

// Per component: read winning edge, mark mask, hook parent, reset minkey.
// 4 consecutive vertices/thread with ulonglong4/int4 streaming loads (1948 ->
// 488 blocks). The full-NV parent sweep (pr=c default) is load-bearing: it
// flattens stale hooks so rootOf only chases this round's forest. Also zeroes
// cnt[zpar] (the list buffer the just-finished scan consumed, which the NEXT
// scan will emit into). NV % 4 == 0, so each in-range thread covers c0..c0+3.
__global__ __launch_bounds__(256) void select_kernel(const int* __restrict__ comp,
                                                     int* __restrict__ parent,
                                                     ull* __restrict__ minkey,
                                                     unsigned char* __restrict__ mask,
                                                     const int* __restrict__ foundCur,
                                                     int* __restrict__ foundNext,
                                                     int* __restrict__ done,
                                                     int* __restrict__ cnt,
                                                     int zpar) {
    int gid = blockIdx.x * 256 + threadIdx.x;
    int b = blockIdx.y;
    int fc = foundCur[b];
    if (gid == 0) {
        foundNext[b] = 0;
        cnt[zpar * NB * CSTR + b * CSTR] = 0;
        if (fc == 0) done[b] = 1;                // monotone; visible to later scans
    }
    if (fc == 0) return;
    int c0 = gid * 4;
    if (c0 >= NV) return;
    size_t off = (size_t)b * NV;
    ulonglong4 kv = *reinterpret_cast<const ulonglong4*>(minkey + off + c0);
    int4 pv = *reinterpret_cast<const int4*>(parent + off + c0);
    ull kk[4] = {kv.x, kv.y, kv.z, kv.w};
    int pold[4] = {pv.x, pv.y, pv.z, pv.w};
    #pragma unroll
    for (int j = 0; j < 4; ++j) {
        int c = c0 + j;
        int pr = c;
        if (kk[j] != ~0ULL) {
            minkey[off + c] = ~0ULL;             // reset only touched slots
            int e = (int)(kk[j] & 0xffffffffu);
            mask[(size_t)b * NE + e] = 1;        // idempotent
            int u, v; index_uv(e, u, v);
            int cu = comp[off + u], cv = comp[off + v];
            pr = (cu == c) ? cv : cu;            // "other" component
        }
        if (pold[j] != pr) parent[off + c] = pr;
    }
}

__global__ __launch_bounds__(256) void count_kernel(const unsigned char* __restrict__ mask,
                                                    int* __restrict__ counts) {
    int b = blockIdx.y, ck = blockIdx.x, t = threadIdx.x;
    const unsigned char* m = mask + (size_t)b * NE;
    int base_e = ck * CHUNK + t * 16;
    int cnt = 0;
    #pragma unroll
    for (int i = 0; i < 16; ++i) {
        int e = base_e + i;
        if (e < NE && m[e]) cnt++;
    }
    __shared__ int sh[256];
    sh[t] = cnt;
    __syncthreads();
    for (int o = 128; o > 0; o >>= 1) {
        if (t < o) sh[t] += sh[t + o];
        __syncthreads();
    }
    if (t == 0) counts[b * NCHUNK + ck] = sh[0];
}

// Write with inline offset computation (reduce over counts[0..ck-1]).
__global__ __launch_bounds__(256) void write_kernel(const unsigned char* __restrict__ mask,
                                                    const int* __restrict__ counts,
                                                    int* __restrict__ out) {
    int b = blockIdx.y, ck = blockIdx.x, t = threadIdx.x;
    __shared__ int sh[256];
    __shared__ int shOff[128];
    shOff[t & 127] = 0;
    __syncthreads();
    if (t < NCHUNK && t < ck) shOff[t] = counts[b * NCHUNK + t];
    __syncthreads();
    for (int o = 64; o > 0; o >>= 1) {
        if (t < o) shOff[t] += shOff[t + o];
        __syncthreads();
    }
    int blockOff = shOff[0];

    const unsigned char* m = mask + (size_t)b * NE;
    int base_e = ck * CHUNK + t * 16;
    int cnt = 0;
    #pragma unroll
    for (int i = 0; i < 16; ++i) {
        int e = base_e + i;
        if (e < NE && m[e]) cnt++;
    }
    sh[t] = cnt;
    __syncthreads();
    for (int o = 1; o < 256; o <<= 1) {          // Hillis-Steele inclusive scan
        int v = 0;
        if (t >= o) v = sh[t - o];
        __syncthreads();
        sh[t] += v;
        __syncthreads();
    }
    int pos = blockOff + (sh[t] - cnt);
    for (int i = 0; i < 16; ++i) {
        int e = base_e + i;
        if (e < NE && m[e]) {
            if (pos < NTREE) out[(size_t)b * NTREE + pos] = e;
            pos++;
        }
    }
}

extern "C" void kernel_launch(void* const* d_in, const int* in_sizes, int n_in,
                              void* d_out, int out_size, void* d_ws, size_t ws_size,
                              hipStream_t stream) {
    const float* fm = (const float*)d_in[0];
    int* out = (int*)d_out;   // reference output dtype is int32

    char* ws = (char*)d_ws;
    size_t off = 0;
    auto alloc = [&](size_t bytes) -> void* {
        void* p = ws + off;
        off += (bytes + 255) & ~(size_t)255;
        return p;
    };
    ull* keys    = (ull*)alloc((size_t)NB * NE * 8);
    ull* minkey  = (ull*)alloc((size_t)NB * NV * 8);
    int* comp    = (int*)alloc((size_t)NB * NV * 4);
    int* parent  = (int*)alloc((size_t)NB * NV * 4);
    unsigned char* mask = (unsigned char*)alloc((size_t)NB * NE);
    int* list0   = (int*)alloc((size_t)NB * NE * 4);
    int* list1   = (int*)alloc((size_t)NB * NE * 4);
    int* cnt     = (int*)alloc(2 * NB * CSTR * 4);
    int* counts  = (int*)alloc((size_t)NB * NCHUNK * 4);
    int* found   = (int*)alloc(2 * NB * 4);
    int* done    = (int*)alloc(NB * 4);

    dim3 blk(256);
    dim3 gE(NEB, NB);
    dim3 gE4(NEB4, NB);
    dim3 gV((NV + 255) / 256, NB);
    dim3 gVS((NV/4 + 255) / 256, NB);     // select: 4 vertices/thread
    dim3 gL(SLB, NB);

    init_kernel<<<gE, blk, 0, stream>>>(comp, parent, minkey, mask, cnt, found, done);
    key0_kernel<<<gV, blk, 0, stream>>>(fm, keys, minkey);

    // Round 0 select (found[0..NB) preset to 1 by init; comp = identity).
    select_kernel<<<gVS, blk, 0, stream>>>(comp, parent, minkey, mask,
                                           found, found + NB, done, cnt, 0);
    // Round 1: full edge sweep + live-edge compaction into list0/cnt[0].
    scan_full_kernel<<<gE4, blk, 0, stream>>>(keys, comp, parent, minkey,
                                              list0, cnt, found + NB);
    select_kernel<<<gVS, blk, 0, stream>>>(comp, parent, minkey, mask,
                                           found + NB, found, done, cnt, 1);
    // Rounds 2..17: list-based scans. scan(r) reads list[r&1], emits
    // list[(r+1)&1]; select(r) zeroes cnt[r&1] for scan(r+1)'s emission.
    for (int r = 2; r < NROUNDS; ++r) {
        int* fCur  = found + (r & 1) * NB;
        int* fNext = found + ((r + 1) & 1) * NB;
        scan_list_kernel<<<gL, blk, 0, stream>>>(keys, comp, parent, minkey,
                                                 list0, list1, cnt, r & 1,
                                                 fCur, done);
        select_kernel<<<gVS, blk, 0, stream>>>(comp, parent, minkey, mask,
                                               fCur, fNext, done, cnt, r & 1);
    }

    count_kernel<<<dim3(NCHUNK, NB), blk, 0, stream>>>(mask, counts);
    write_kernel<<<dim3(NCHUNK, NB), blk, 0, stream>>>(mask, counts, out);
}